// Round 7
// baseline (120.677 us; speedup 1.0000x reference)
//
#include <hip/hip_runtime.h>

#define EPS2 1e-16f

constexpr int H      = 64;
constexpr int PBLOCK = 256;     // prep block size
constexpr int BLOCK  = 256;     // main kernel block
constexpr int NCHUNK = 4;       // sources per thread (S=1024 / 256)
constexpr float LOG2E = 1.4426950408889634f;

__device__ __forceinline__ float rcpf_fast(float x) { return __builtin_amdgcn_rcpf(x); }
__device__ __forceinline__ float rsqf_fast(float x) { return __builtin_amdgcn_rsqf(x); }
__device__ __forceinline__ float exp2_fast(float x) { return __builtin_amdgcn_exp2f(x); }

// ws layout (floats):
//   [0, 1024)              wpk: per-h 16-float records (pre-folded scales)
//   [1024, 1024+4S)        sPA: {px*invL, py*invL, pz*invL, area}
//   [1024+4S, 1024+8S)     sNB: {nhx, nhy, nhz, log2(n2)}
//   [1024+8S, 1024+9S)     sw : strengths
//
// Weight folding (exact algebra):
//   a_reg = -log2e * a_true  -> e = exp2(a_reg) = exp(-a_true); sg = rcp(1+e)
//   p[1],p[2] = -0.5*W1      (log2-features absorb ln2)
//   p[8..11] = -2*W2         (so o_reg = 2*log2e*o_true exactly; ln2*log2e cancels)
//   tanh(o_true) = (E-1)/(E+1), E = exp2(o_reg)
__global__ void prep(const float* __restrict__ refLenP,
                     const float* __restrict__ srcP,
                     const float* __restrict__ srcN,
                     const float* __restrict__ wgtP,
                     const float* __restrict__ areaP,
                     const float* __restrict__ W1,
                     const float* __restrict__ b1,
                     const float* __restrict__ W2,
                     float* __restrict__ ws, int S)
{
    const int nSrcBlk = (S + PBLOCK - 1) / PBLOCK;
    const int bid = blockIdx.x;
    if (bid < nSrcBlk) {
        const int s = bid * PBLOCK + threadIdx.x;
        if (s < S) {
            const float invL = rcpf_fast(refLenP[0]);
            float px = srcP[s * 3 + 0] * invL;
            float py = srcP[s * 3 + 1] * invL;
            float pz = srcP[s * 3 + 2] * invL;
            float nx = srcN[s * 3 + 0];
            float ny = srcN[s * 3 + 1];
            float nz = srcN[s * 3 + 2];
            float n2 = fmaf(nx, nx, fmaf(ny, ny, nz * nz)) + EPS2;
            float inv_n = rsqf_fast(n2);
            float l2n = __log2f(n2);
            float4* sPA = (float4*)(ws + 1024);
            float4* sNB = (float4*)(ws + 1024 + 4 * S);
            float*  sw  = ws + 1024 + 8 * S;
            sPA[s] = make_float4(px, py, pz, areaP[s]);
            sNB[s] = make_float4(nx * inv_n, ny * inv_n, nz * inv_n, l2n);
            sw[s]  = wgtP[s];
        }
    } else {
        const int h = threadIdx.x;
        if (h < H) {
            float* p = ws + h * 16;
            p[0] = -LOG2E * W1[0 * H + h];     // area
            p[1] = -0.5f  * W1[1 * H + h];     // * log2(r2)
            p[2] = -0.5f  * W1[2 * H + h];     // * log2(n2)
            p[3] = -LOG2E * W1[3 * H + h];     // P1..P4
            p[4] = -LOG2E * W1[4 * H + h];
            p[5] = -LOG2E * W1[5 * H + h];
            p[6] = -LOG2E * b1[h];             // note: slot 6 now b1 (see below)
            p[7] = -LOG2E * W1[6 * H + h];     // P4 coeff moved to slot 7
            p[8]  = -2.0f * W2[h * 4 + 0];
            p[9]  = -2.0f * W2[h * 4 + 1];
            p[10] = -2.0f * W2[h * 4 + 2];
            p[11] = -2.0f * W2[h * 4 + 3];
            p[12] = 0.f; p[13] = 0.f; p[14] = 0.f; p[15] = 0.f;
        }
    }
}

__global__ __launch_bounds__(BLOCK)
void bh_kernel(const float* __restrict__ refLenP,
               const float* __restrict__ tgtP,
               const float* __restrict__ b2,
               const float* __restrict__ ws,
               float* __restrict__ out,
               int S, int T)
{
    __shared__ float red[4][4];

    const int tid = threadIdx.x;
    const int t = blockIdx.x;

    const float invL = rcpf_fast(refLenP[0]);
    const float tx = tgtP[t * 3 + 0] * invL;
    const float ty = tgtP[t * 3 + 1] * invL;
    const float tz = tgtP[t * 3 + 2] * invL;

    const float4* __restrict__ sPA = (const float4*)(ws + 1024);
    const float4* __restrict__ sNB = (const float4*)(ws + 1024 + 4 * S);
    const float*  __restrict__ sw  = ws + 1024 + 8 * S;
    const float4* __restrict__ wq  = (const float4*)ws;

    // ---- Phase A: per-pair features (scalar; 7 regs/chunk) ----
    float f1[NCHUNK], f3[NCHUNK], f4[NCHUNK], f5[NCHUNK], f6[NCHUNK];
    float fa[NCHUNK], f2s[NCHUNK];
    #pragma unroll
    for (int c = 0; c < NCHUNK; ++c) {
        const int s = tid + c * BLOCK;
        const int sc = (s < S) ? s : (S - 1);
        const float4 pa = sPA[sc];
        const float4 nb = sNB[sc];
        float rx = tx - pa.x;
        float ry = ty - pa.y;
        float rz = tz - pa.z;
        float r2 = fmaf(rx, rx, fmaf(ry, ry, fmaf(rz, rz, EPS2)));
        float ir = rsqf_fast(r2);
        f1[c] = __log2f(r2);
        float cosv = fmaf(rx, nb.x, fmaf(ry, nb.y, rz * nb.z)) * ir;
        float c2 = cosv * cosv;
        fa[c]  = pa.w;
        f2s[c] = nb.w;
        f3[c] = cosv;
        f4[c] = fmaf(c2, 1.5f, -0.5f);
        f5[c] = (c2 * 2.5f - 1.5f) * cosv;
        f6[c] = fmaf(fmaf(c2, 4.375f, -3.75f), c2, 0.375f);
    }

    // ---- Phase B: fused MLP (folded scales; raw v_exp_f32) ----
    float o0[NCHUNK], o1[NCHUNK], o2[NCHUNK], o3[NCHUNK];
    {
        const float s2 = 2.0f * LOG2E;
        const float b20 = s2 * b2[0], b21 = s2 * b2[1];
        const float b22 = s2 * b2[2], b23 = s2 * b2[3];
        #pragma unroll
        for (int c = 0; c < NCHUNK; ++c) {
            o0[c] = b20; o1[c] = b21; o2[c] = b22; o3[c] = b23;
        }
    }

    #pragma unroll 4
    for (int h = 0; h < H; ++h) {
        const float4 wa = wq[h * 4 + 0];   // {w_area, w_logr, w_logn, w_P1}
        const float4 wb = wq[h * 4 + 1];   // {w_P2, w_P3, b1, w_P4}
        const float4 w2 = wq[h * 4 + 2];   // -2*W2 row
        #pragma unroll
        for (int c = 0; c < NCHUNK; ++c) {
            float a = fmaf(fa[c], wa.x, fmaf(f2s[c], wa.z, wb.z));
            a = fmaf(f1[c], wa.y, a);
            a = fmaf(f3[c], wa.w, a);
            a = fmaf(f4[c], wb.x, a);
            a = fmaf(f5[c], wb.y, a);
            a = fmaf(f6[c], wb.w, a);
            float e  = exp2_fast(a);           // = exp(-a_true)
            float sg = rcpf_fast(1.0f + e);    // sigmoid(a_true)
            float hv = a * sg;                 // = -log2e * silu_true
            o0[c] = fmaf(hv, w2.x, o0[c]);
            o1[c] = fmaf(hv, w2.y, o1[c]);
            o2[c] = fmaf(hv, w2.z, o2[c]);
            o3[c] = fmaf(hv, w2.w, o3[c]);
        }
    }

    // ---- Phase C: epilogue (geometry recomputed from L1-hot loads) ----
    float acc0 = 0.f, acc1 = 0.f, acc2 = 0.f, acc3 = 0.f;
    #pragma unroll
    for (int c = 0; c < NCHUNK; ++c) {
        const int s = tid + c * BLOCK;
        const int sc = (s < S) ? s : (S - 1);
        const float4 pa = sPA[sc];
        const float4 nb = sNB[sc];
        const float wgt = (s < S) ? sw[sc] : 0.0f;
        float rx = tx - pa.x;
        float ry = ty - pa.y;
        float rz = tz - pa.z;
        float r2 = fmaf(rx, rx, fmaf(ry, ry, fmaf(rz, rz, EPS2)));
        float ir = rsqf_fast(r2);
        float wsv = wgt * ir;       // w * inv_r
        float wvv = wsv * ir;       // w * inv_r^2

        // tanh(o_true) = (E-1)/(E+1), E = 2^{o_reg}
        float tt[4];
        float oo[4] = {o0[c], o1[c], o2[c], o3[c]};
        #pragma unroll
        for (int k = 0; k < 4; ++k) {
            float m = fminf(fmaxf(oo[k], -126.f), 126.f);
            float E = exp2_fast(m);
            tt[k] = (E - 1.0f) * rcpf_fast(E + 1.0f);
        }

        acc0 = fmaf(wsv, tt[0], acc0);
        float rhx = rx * ir, rhy = ry * ir, rhz = rz * ir;
        float cxx = rhy * nb.z - rhz * nb.y;
        float cxy = rhz * nb.x - rhx * nb.z;
        float cxz = rhx * nb.y - rhy * nb.x;
        float vx = tt[1] * rhx + tt[2] * nb.x + tt[3] * cxx;
        float vy = tt[1] * rhy + tt[2] * nb.y + tt[3] * cxy;
        float vz = tt[1] * rhz + tt[2] * nb.z + tt[3] * cxz;
        acc1 = fmaf(wvv, vx, acc1);
        acc2 = fmaf(wvv, vy, acc2);
        acc3 = fmaf(wvv, vz, acc3);
    }

    // ---- Phase D: reduction (wave shuffle, then LDS across 4 waves) ----
    #pragma unroll
    for (int off = 32; off > 0; off >>= 1) {
        acc0 += __shfl_down(acc0, off);
        acc1 += __shfl_down(acc1, off);
        acc2 += __shfl_down(acc2, off);
        acc3 += __shfl_down(acc3, off);
    }
    const int wave = tid >> 6;
    const int lane = tid & 63;
    if (lane == 0) {
        red[wave][0] = acc0; red[wave][1] = acc1;
        red[wave][2] = acc2; red[wave][3] = acc3;
    }
    __syncthreads();
    if (tid < 4) {
        float v = red[0][tid] + red[1][tid] + red[2][tid] + red[3][tid];
        out[t * 4 + tid] = v;
    }
}

extern "C" void kernel_launch(void* const* d_in, const int* in_sizes, int n_in,
                              void* d_out, int out_size, void* d_ws, size_t ws_size,
                              hipStream_t stream) {
    const float* refLen = (const float*)d_in[0];
    const float* srcP   = (const float*)d_in[1];
    const float* tgtP   = (const float*)d_in[2];
    const float* w      = (const float*)d_in[3];
    const float* area   = (const float*)d_in[4];
    const float* srcN   = (const float*)d_in[5];
    const float* W1     = (const float*)d_in[6];
    const float* b1     = (const float*)d_in[7];
    const float* W2     = (const float*)d_in[8];
    const float* b2     = (const float*)d_in[9];
    float* out          = (float*)d_out;
    float* ws           = (float*)d_ws;

    const int S = in_sizes[3];
    const int T = in_sizes[2] / 3;
    const int nSrcBlk = (S + PBLOCK - 1) / PBLOCK;

    prep<<<nSrcBlk + 1, PBLOCK, 0, stream>>>(refLen, srcP, srcN, w, area, W1, b1, W2, ws, S);
    bh_kernel<<<T, BLOCK, 0, stream>>>(refLen, tgtP, b2, ws, out, S, T);
}

// Round 8
// 110.223 us; speedup vs baseline: 1.0948x; 1.0948x over previous
//
#include <hip/hip_runtime.h>

typedef __attribute__((ext_vector_type(4))) float f32x4;
typedef __attribute__((ext_vector_type(8))) short bf16x8;

#define EPS2 1e-16f
constexpr int PBLOCK = 256;
constexpr int BLOCK  = 256;   // 4 waves; 1 target per block
constexpr float LOG2E = 1.4426950408889634f;

__device__ __forceinline__ float rcpf_fast(float x){ return __builtin_amdgcn_rcpf(x); }
__device__ __forceinline__ float rsqf_fast(float x){ return __builtin_amdgcn_rsqf(x); }
__device__ __forceinline__ float exp2_fast(float x){ return __builtin_amdgcn_exp2f(x); }
__device__ __forceinline__ unsigned cvt_pk_bf16(float lo, float hi){
    unsigned d;
    asm("v_cvt_pk_bf16_f32 %0, %1, %2" : "=v"(d) : "v"(lo), "v"(hi));
    return d;
}
__device__ __forceinline__ bf16x8 as_frag(int4 v){
    union { int4 i; bf16x8 f; } u; u.i = v; return u.f;
}

// ws layout (floats):
//   [0,256)      W1' fragments: u32[h=64][4]  (8 bf16 per h: folded W1 row + bias)
//   [256,384)    W2t: u32[j=4][32]            (64 bf16 per j: -2*W2[:,j])
//   [384,384+4S) sPA float4: {px*invL, py*invL, pz*invL, area}
//   [+4S,+8S)    sNB float4: {nhx, nhy, nhz, log2(n2)}
//   [+8S,+9S)    sw: strengths
//
// Algebra (exact, as rounds 5-7): a_reg = -log2e*a_true (features carry log2(r2));
// hv_reg = a_reg*sigmoid(a_true) = -log2e*silu; W2'' = -2*W2 so
// o_reg = 2*log2e*o_true; tanh(o_true) = (E-1)/(E+1), E = exp2(o_reg).
__global__ void prep(const float* __restrict__ refLenP,
                     const float* __restrict__ srcP,
                     const float* __restrict__ srcN,
                     const float* __restrict__ wgtP,
                     const float* __restrict__ areaP,
                     const float* __restrict__ W1,
                     const float* __restrict__ b1,
                     const float* __restrict__ W2,
                     float* __restrict__ ws, int S)
{
    const int nSrcBlk = (S + PBLOCK - 1) / PBLOCK;
    const int bid = blockIdx.x;
    if (bid < nSrcBlk) {
        const int s = bid * PBLOCK + threadIdx.x;
        if (s < S) {
            const float invL = rcpf_fast(refLenP[0]);
            float px = srcP[s*3+0]*invL, py = srcP[s*3+1]*invL, pz = srcP[s*3+2]*invL;
            float nx = srcN[s*3+0], ny = srcN[s*3+1], nz = srcN[s*3+2];
            float n2 = fmaf(nx,nx, fmaf(ny,ny, nz*nz)) + EPS2;
            float inv_n = rsqf_fast(n2);
            float l2n = __log2f(n2);
            float4* sPA = (float4*)(ws + 384);
            float4* sNB = (float4*)(ws + 384 + 4*S);
            float*  sw  = ws + 384 + 8*S;
            sPA[s] = make_float4(px, py, pz, areaP[s]);
            sNB[s] = make_float4(nx*inv_n, ny*inv_n, nz*inv_n, l2n);
            sw[s]  = wgtP[s];
        }
    } else {
        const int t = threadIdx.x;
        unsigned* W1u = (unsigned*)ws;
        unsigned* W2u = (unsigned*)ws + 256;
        if (t < 64) {
            const int h = t;
            float v[8];
            v[0] = -LOG2E * W1[0*64 + h];   // area
            v[1] = -0.5f  * W1[1*64 + h];   // * log2(r2)
            v[2] = -0.5f  * W1[2*64 + h];   // * log2(n2)
            v[3] = -LOG2E * W1[3*64 + h];   // P1 (= cos)
            v[4] = -LOG2E * W1[4*64 + h];   // P2
            v[5] = -LOG2E * W1[5*64 + h];   // P3
            v[6] = -LOG2E * W1[6*64 + h];   // P4
            v[7] = -LOG2E * b1[h];          // bias (feature 7 == 1.0)
            #pragma unroll
            for (int r = 0; r < 4; ++r)
                W1u[h*4 + r] = cvt_pk_bf16(v[2*r], v[2*r+1]);
        } else if (t < 192) {
            const int idx = t - 64;
            const int j = idx >> 5;          // output col 0..3
            const int hp = idx & 31;         // h-pair
            float a = -2.0f * W2[(2*hp  )*4 + j];
            float b = -2.0f * W2[(2*hp+1)*4 + j];
            W2u[j*32 + hp] = cvt_pk_bf16(a, b);
        }
    }
}

__global__ __launch_bounds__(BLOCK)
void bh_kernel(const float* __restrict__ refLenP,
               const float* __restrict__ tgtP,
               const float* __restrict__ b2,
               const float* __restrict__ ws,
               float* __restrict__ out,
               int S, int T)
{
    // All LDS regions are WAVE-PRIVATE (indexed by wave) -> no barriers needed;
    // compiler orders aliasing DS ops with lgkmcnt.
    __shared__ unsigned featsL[4][64][4];     // per-pair packed bf16 features
    __shared__ unsigned hvL[4][16][36];       // hv^T: [paircol][h-pair], pad 36 (16B-aligned rows)
    __shared__ f32x4   oL[4][64];             // o_reg per pair
    __shared__ float   red[4][4];

    const int tid = threadIdx.x;
    const int wv  = tid >> 6;
    const int l   = tid & 63;
    const int col = l & 15;
    const int q   = l >> 4;
    const int t   = blockIdx.x;

    const unsigned* __restrict__ W1u = (const unsigned*)ws;
    const unsigned* __restrict__ W2u = (const unsigned*)ws + 256;
    const float4* __restrict__ sPA = (const float4*)(ws + 384);
    const float4* __restrict__ sNB = (const float4*)(ws + 384 + 4*S);
    const float*  __restrict__ sw  = ws + 384 + 8*S;

    // A1 fragments: A = W1' [64h x 8k] (K=32, real k 0..7 -> q==0 lanes only)
    int4 A1[4];
    #pragma unroll
    for (int mt = 0; mt < 4; ++mt) {
        int4 r = *(const int4*)&W1u[(mt*16 + col) * 4];
        A1[mt] = (q == 0) ? r : make_int4(0,0,0,0);
    }
    // A2 fragments: A = W2'' [16j x 64h] (rows 0..3 real), K-tiles kt=0,1
    int4 A2[2];
    #pragma unroll
    for (int kt = 0; kt < 2; ++kt) {
        const int rowj = col;
        const int src = (rowj < 4) ? rowj : 0;
        int4 r = *(const int4*)&W2u[src*32 + kt*16 + q*4];
        A2[kt] = (rowj < 4) ? r : make_int4(0,0,0,0);
    }

    const float invL = rcpf_fast(refLenP[0]);
    const float tx = tgtP[t*3+0]*invL;
    const float ty = tgtP[t*3+1]*invL;
    const float tz = tgtP[t*3+2]*invL;
    const float s2 = 2.0f * LOG2E;
    const f32x4 b2init = { s2*b2[0], s2*b2[1], s2*b2[2], s2*b2[3] };
    const f32x4 zero4  = { 0.f, 0.f, 0.f, 0.f };

    float acc0 = 0.f, acc1 = 0.f, acc2 = 0.f, acc3 = 0.f;

    for (int it = 0; it < 4; ++it) {
        const int s  = wv*256 + it*64 + l;     // this lane's source/pair
        const int sc = (s < S) ? s : 0;
        const float4 pa = sPA[sc];
        const float4 nb = sNB[sc];
        const float wgt = (s < S) ? sw[sc] : 0.f;

        // ---- features for my pair ----
        float rx = tx - pa.x, ry = ty - pa.y, rz = tz - pa.z;
        float r2 = fmaf(rx,rx, fmaf(ry,ry, fmaf(rz,rz, EPS2)));
        float ir = rsqf_fast(r2);
        float l2r = __log2f(r2);
        float cosv = fmaf(rx,nb.x, fmaf(ry,nb.y, rz*nb.z)) * ir;
        float c2 = cosv * cosv;
        float P2 = fmaf(c2, 1.5f, -0.5f);
        float P3 = (c2*2.5f - 1.5f) * cosv;
        float P4 = fmaf(fmaf(c2, 4.375f, -3.75f), c2, 0.375f);
        unsigned f01 = cvt_pk_bf16(pa.w, l2r);
        unsigned f23 = cvt_pk_bf16(nb.w, cosv);
        unsigned f45 = cvt_pk_bf16(P2,   P3);
        unsigned f67 = cvt_pk_bf16(P4,   1.0f);
        *(int4*)&featsL[wv][l][0] = make_int4((int)f01, (int)f23, (int)f45, (int)f67);

        // ---- 4 pair-blocks of 16 ----
        #pragma unroll
        for (int pb = 0; pb < 4; ++pb) {
            // B1: feats^T frag — col = pair, k = feature (q==0 real, else 0)
            int4 braw = *(const int4*)&featsL[wv][pb*16 + col][0];
            int4 b1i = (q == 0) ? braw : make_int4(0,0,0,0);
            bf16x8 B1 = as_frag(b1i);

            // GEMM1 (4 M-tiles of h) + silu + pack hv^T into LDS
            #pragma unroll
            for (int mt = 0; mt < 4; ++mt) {
                f32x4 c1 = __builtin_amdgcn_mfma_f32_16x16x32_bf16(
                               as_frag(A1[mt]), B1, zero4, 0, 0, 0);
                float hv0, hv1, hv2, hv3;
                { float e = exp2_fast(c1[0]); hv0 = c1[0] * rcpf_fast(1.0f + e); }
                { float e = exp2_fast(c1[1]); hv1 = c1[1] * rcpf_fast(1.0f + e); }
                { float e = exp2_fast(c1[2]); hv2 = c1[2] * rcpf_fast(1.0f + e); }
                { float e = exp2_fast(c1[3]); hv3 = c1[3] * rcpf_fast(1.0f + e); }
                unsigned h01 = cvt_pk_bf16(hv0, hv1);
                unsigned h23 = cvt_pk_bf16(hv2, hv3);
                *(uint2*)&hvL[wv][col][mt*8 + q*2] = make_uint2(h01, h23);
            }

            // GEMM2: o^T[j][pair] = W2'' · hv^T   (K = 64 -> 2 K-tiles)
            f32x4 oacc = b2init;
            #pragma unroll
            for (int kt = 0; kt < 2; ++kt) {
                int4 b2raw = *(const int4*)&hvL[wv][col][kt*16 + q*4];
                oacc = __builtin_amdgcn_mfma_f32_16x16x32_bf16(
                           as_frag(A2[kt]), as_frag(b2raw), oacc, 0, 0, 0);
            }
            if (q == 0) oL[wv][pb*16 + col] = oacc;   // rows j=0..3 live in q==0 lanes
        }

        // ---- epilogue: my pair's o_reg -> tanh -> weighted accumulation ----
        f32x4 ov = oL[wv][l];
        float tt[4];
        #pragma unroll
        for (int k = 0; k < 4; ++k) {
            float m = fminf(fmaxf(ov[k], -126.f), 126.f);
            float E = exp2_fast(m);
            tt[k] = (E - 1.0f) * rcpf_fast(E + 1.0f);
        }
        float wsv = wgt * ir;        // w * inv_r
        float wvv = wsv * ir;        // w * inv_r^2
        acc0 = fmaf(wsv, tt[0], acc0);
        float rhx = rx*ir, rhy = ry*ir, rhz = rz*ir;
        float cxx = rhy*nb.z - rhz*nb.y;
        float cxy = rhz*nb.x - rhx*nb.z;
        float cxz = rhx*nb.y - rhy*nb.x;
        float vx = tt[1]*rhx + tt[2]*nb.x + tt[3]*cxx;
        float vy = tt[1]*rhy + tt[2]*nb.y + tt[3]*cxy;
        float vz = tt[1]*rhz + tt[2]*nb.z + tt[3]*cxz;
        acc1 = fmaf(wvv, vx, acc1);
        acc2 = fmaf(wvv, vy, acc2);
        acc3 = fmaf(wvv, vz, acc3);
    }

    // ---- block reduction ----
    #pragma unroll
    for (int off = 32; off > 0; off >>= 1) {
        acc0 += __shfl_down(acc0, off);
        acc1 += __shfl_down(acc1, off);
        acc2 += __shfl_down(acc2, off);
        acc3 += __shfl_down(acc3, off);
    }
    if ((tid & 63) == 0) {
        red[wv][0] = acc0; red[wv][1] = acc1;
        red[wv][2] = acc2; red[wv][3] = acc3;
    }
    __syncthreads();
    if (tid < 4) {
        float v = red[0][tid] + red[1][tid] + red[2][tid] + red[3][tid];
        out[t*4 + tid] = v;
    }
}

extern "C" void kernel_launch(void* const* d_in, const int* in_sizes, int n_in,
                              void* d_out, int out_size, void* d_ws, size_t ws_size,
                              hipStream_t stream) {
    const float* refLen = (const float*)d_in[0];
    const float* srcP   = (const float*)d_in[1];
    const float* tgtP   = (const float*)d_in[2];
    const float* w      = (const float*)d_in[3];
    const float* area   = (const float*)d_in[4];
    const float* srcN   = (const float*)d_in[5];
    const float* W1     = (const float*)d_in[6];
    const float* b1     = (const float*)d_in[7];
    const float* W2     = (const float*)d_in[8];
    const float* b2     = (const float*)d_in[9];
    float* out          = (float*)d_out;
    float* ws           = (float*)d_ws;

    const int S = in_sizes[3];
    const int T = in_sizes[2] / 3;
    const int nSrcBlk = (S + PBLOCK - 1) / PBLOCK;

    prep<<<nSrcBlk + 1, PBLOCK, 0, stream>>>(refLen, srcP, srcN, w, area, W1, b1, W2, ws, S);
    bh_kernel<<<T, BLOCK, 0, stream>>>(refLen, tgtP, b2, ws, out, S, T);
}